// Round 1
// baseline (392.527 us; speedup 1.0000x reference)
//
#include <hip/hip_runtime.h>
#include <hip/hip_bf16.h>
#include <cstdint>

#define BATCH   4096
#define IN_DIM  1024
#define OUT_DIM 1024
#define NEXP    16

typedef __bf16 bf16;
typedef __attribute__((ext_vector_type(8))) __bf16 bf16x8;
typedef __attribute__((ext_vector_type(4))) float  f32x4;

#define AS1 __attribute__((address_space(1)))
#define AS3 __attribute__((address_space(3)))

__device__ __forceinline__ void gld_lds16(const bf16* g, bf16* l) {
    __builtin_amdgcn_global_load_lds((const AS1 void*)g, (AS3 void*)l, 16, 0, 0);
}

// Static counted waits (T4). "memory" clobber = compiler fence so no memory
// op (gld_lds issue, ds_read) can be moved across the wait/barrier pair.
__device__ __forceinline__ void wait_vm0() { asm volatile("s_waitcnt vmcnt(0)" ::: "memory"); }
__device__ __forceinline__ void wait_vm2() { asm volatile("s_waitcnt vmcnt(2)" ::: "memory"); }
__device__ __forceinline__ void wait_vm4() { asm volatile("s_waitcnt vmcnt(4)" ::: "memory"); }
__device__ __forceinline__ void wait_vm8() { asm volatile("s_waitcnt vmcnt(8)" ::: "memory"); }

// ---------------------------------------------------------------------------
// Merged conversion kernel.
// Blocks [0,4096): weight fp32 -> fragment-ordered bf16 tiles, now via an
//   LDS transpose so global reads are coalesced f32x4 row reads (the old
//   version did 16 scalar loads/thread at 4KB stride).
//   Tile (nblk, ne, ks) = 64k x 64o. Chunk c = sub*64 + lane,
//   sub = kk*4 + wn*2 + nt, holds W[ne*1024+ks*64+kk*32+lq*8+j][nblk*64+
//   wn*32+nt*16+lr] at byte c*16+2j  (identical layout to before).
// Blocks [4096,4608): x fp32 -> 512 pre-tiled swizzled bf16 images
//   (unchanged from previous version).
// ---------------------------------------------------------------------------
__global__ __launch_bounds__(256) void convert_all(
        const float* __restrict__ x, const float* __restrict__ W,
        bf16* __restrict__ xt, bf16* __restrict__ wt) {
    __shared__ float Ls[64][65];       // pad 65: read phase is 2-way (free)
    int t = threadIdx.x;
    int bid = blockIdx.x;
    if (bid < 4096) {
        int nblk = bid >> 8, ne = (bid >> 4) & 15, ks = bid & 15;
        int kb = ne * 1024 + ks * 64;
        int n0 = nblk * 64;
#pragma unroll
        for (int r = 0; r < 4; r++) {
            int idx = r * 256 + t;             // 1024 f32x4 = 64x64 tile
            int row = idx >> 4, c4 = (idx & 15) * 4;
            f32x4 v = *(const f32x4*)(W + (size_t)(kb + row) * OUT_DIM + n0 + c4);
#pragma unroll
            for (int j = 0; j < 4; j++) Ls[row][c4 + j] = v[j];
        }
        __syncthreads();
#pragma unroll
        for (int r = 0; r < 2; r++) {
            int c = r * 256 + t;               // 0..511
            int sub = c >> 6, l = c & 63;
            int lr = l & 15, lq = l >> 4;
            int kk = sub >> 2, wn = (sub >> 1) & 1, nt = sub & 1;
            int krow = kk * 32 + lq * 8;
            int col = wn * 32 + nt * 16 + lr;
            bf16x8 v;
#pragma unroll
            for (int j = 0; j < 8; j++) v[j] = (bf16)Ls[krow + j][col];
            *(bf16x8*)(wt + (size_t)bid * 4096 + c * 8) = v;
        }
    } else {
        int tile = bid - 4096;                 // 512
        int mblk = tile >> 4, ks = tile & 15;
#pragma unroll
        for (int r = 0; r < 4; r++) {
            int q = r * 256 + t;
            int m_loc = q >> 3, sc = q & 7;
            int cc = sc ^ (m_loc & 7);
            const float* src = x + (size_t)(mblk * 128 + m_loc) * IN_DIM + ks * 64 + cc * 8;
            f32x4 a = *(const f32x4*)src;
            f32x4 b = *(const f32x4*)(src + 4);
            bf16x8 v;
#pragma unroll
            for (int j = 0; j < 4; j++) { v[j] = (bf16)a[j]; v[4 + j] = (bf16)b[j]; }
            *(bf16x8*)(xt + (size_t)tile * 8192 + q * 8) = v;
        }
    }
}

// ---------------------------------------------------------------------------
// GEMM with counted-vmcnt pipeline (T3+T4) + setprio (T5).
// K-step index g = ks*16 + ne (256 steps). B tile g staged in Bs[g&3]
// (4 bufs), A tile ks in As[ks&1] (2 bufs). Prefetch distance 2 for B;
// A(ks+1) issued at ne==13. ONE raw s_barrier per step, never vmcnt(0)
// in the main loop.
//   Safety: writes issued at step g target the buffer last READ at step
//   g-2; the barrier at step g-1 orders those reads before this issue.
//   Read of Bs[g&3] is covered by own-wave vmcnt(N) + barrier.
//   N (in-flight after target): steady {B(g+1),B(g+2)}=4; ne 13/14/15 of
//   ks<15 add the 4 A loads -> 8; tail ks==15: 4,4,...,4,2,0.
// Block 128m x 64n, 4 waves (2x2), wave tile 64x32, mfma 16x16x32 bf16.
// LDS 71.5 KB -> 2 blocks/CU (grid is 2/CU anyway).
// ---------------------------------------------------------------------------
__global__ __launch_bounds__(256, 2) void moe_gemm(
        const float* __restrict__ cw, const float* __restrict__ bias,
        const bf16* __restrict__ xt, const bf16* __restrict__ wt,
        float* __restrict__ out) {
    int nblk = blockIdx.x;                 // 16 -> bid%8 clusters nblk per XCD
    int mblk = blockIdx.y;                 // 32
    int m0 = mblk * 128, n0 = nblk * 64;
    int t = threadIdx.x;
    int lane = t & 63, w = t >> 6;
    int wm = w >> 1, wn = w & 1;
    int lq = lane >> 4, lr = lane & 15;

    __shared__ bf16 As[2][128 * 64];       // 2 x 16 KB swizzled A images
    __shared__ bf16 Bs[4][64 * 64];        // 4 x 8 KB fragment-ordered B tiles
    __shared__ float cwT[16 * 132];        // cwT[ne][row], stride 132 (banks)

    // transpose cw panel into LDS once (global loads drained by syncthreads
    // BEFORE any pipeline stage is issued, so the drain is harmless)
#pragma unroll
    for (int r = 0; r < 2; r++) {
        int q = r * 256 + t;               // 512 f32x4 = 2048 floats
        f32x4 v = *(const f32x4*)(cw + (size_t)m0 * NEXP + q * 4);
        int row = q >> 2, nb = (q & 3) * 4;
#pragma unroll
        for (int c2 = 0; c2 < 4; c2++) cwT[(nb + c2) * 132 + row] = v[c2];
    }
    __syncthreads();

    const bf16* abase = xt + (size_t)(mblk * 16) * 8192;
    const bf16* bbase = wt + (size_t)nblk * (16 * 16 * 4096);

    // prologue: issue A(ks=0) [4 loads], B(g=0) [2], B(g=1) [2]
    {
        const bf16* a0 = abase + t * 8;
#pragma unroll
        for (int r = 0; r < 4; r++) gld_lds16(a0 + r * 2048, &As[0][r * 2048 + t * 8]);
        const bf16* b0 = bbase + t * 8;                    // tile (ne=0,ks=0)
#pragma unroll
        for (int r = 0; r < 2; r++) gld_lds16(b0 + r * 2048, &Bs[0][r * 2048 + t * 8]);
        const bf16* b1 = bbase + (size_t)16 * 4096 + t * 8; // tile (ne=1,ks=0)
#pragma unroll
        for (int r = 0; r < 2; r++) gld_lds16(b1 + r * 2048, &Bs[1][r * 2048 + t * 8]);
    }

    const f32x4 fz = {0.f, 0.f, 0.f, 0.f};
    f32x4 acc[4][2];
#pragma unroll
    for (int mt = 0; mt < 4; mt++)
#pragma unroll
        for (int nt = 0; nt < 2; nt++) acc[mt][nt] = fz;

    int swz = lr & 7;
    int mrow[4];
#pragma unroll
    for (int mt = 0; mt < 4; mt++) mrow[mt] = (wm * 64 + mt * 16 + lr) * 64;

    bf16x8 af[4][2];                       // A frags, live across one ks

    // one pipeline step; all args compile-time under the unrolled loops
    auto step = [&](int ne, int ks, bool stage_b, bool stage_a, int wsel) {
        if (stage_b) {                     // issue B(g+2)
            int ks2 = ks + ((ne + 2) >> 4);
            int ne2 = (ne + 2) & 15;
            const bf16* bn = bbase + (size_t)(ne2 * 16 + ks2) * 4096 + t * 8;
            bf16* dst = &Bs[(ne + 2) & 3][t * 8];
#pragma unroll
            for (int r = 0; r < 2; r++) gld_lds16(bn + r * 2048, dst + r * 2048);
        }
        if (stage_a) {                     // issue A(ks+1) at ne==13
            const bf16* an = abase + (size_t)(ks + 1) * 8192 + t * 8;
            bf16* dst = &As[(ks + 1) & 1][t * 8];
#pragma unroll
            for (int r = 0; r < 4; r++) gld_lds16(an + r * 2048, dst + r * 2048);
        }
        if (wsel == 0) wait_vm4();
        else if (wsel == 1) wait_vm8();
        else if (wsel == 2) wait_vm2();
        else wait_vm0();
        __builtin_amdgcn_s_barrier();
        asm volatile("" ::: "memory");

        if (ne == 0) {                     // A frags -> regs, reused over 16 ne
#pragma unroll
            for (int kk = 0; kk < 2; kk++)
#pragma unroll
                for (int mt = 0; mt < 4; mt++)
                    af[mt][kk] = *(const bf16x8*)
                        &As[ks & 1][mrow[mt] + ((kk * 4 + lq) ^ swz) * 8];
        }
        // B fragments (linear, conflict-free)
        bf16x8 bfr[2][2];
#pragma unroll
        for (int kk = 0; kk < 2; kk++)
#pragma unroll
            for (int nt = 0; nt < 2; nt++)
                bfr[kk][nt] = *(const bf16x8*)
                    &Bs[ne & 3][((kk * 2 + wn) * 2 + nt) * 512 + lane * 8];
        // scales for this expert (broadcast within quads)
        f32x4 s[4];
#pragma unroll
        for (int mt = 0; mt < 4; mt++)
            s[mt] = *(const f32x4*)&cwT[ne * 132 + wm * 64 + mt * 16 + lq * 4];
        // MFMA + immediate fold
        __builtin_amdgcn_s_setprio(1);
#pragma unroll
        for (int mt = 0; mt < 4; mt++)
#pragma unroll
            for (int nt = 0; nt < 2; nt++) {
                f32x4 p = __builtin_amdgcn_mfma_f32_16x16x32_bf16(
                    af[mt][0], bfr[0][nt], fz, 0, 0, 0);
                p = __builtin_amdgcn_mfma_f32_16x16x32_bf16(
                    af[mt][1], bfr[1][nt], p, 0, 0, 0);
                acc[mt][nt] += s[mt] * p;  // v_pk_fma_f32 x2
            }
        __builtin_amdgcn_s_setprio(0);
    };

    for (int ks = 0; ks < 15; ks++) {
#pragma unroll
        for (int ne = 0; ne < 16; ne++)
            step(ne, ks, true, ne == 13, (ne >= 13) ? 1 : 0);
    }
    // peeled ks == 15: no A prefetch, B issue only while g+2 <= 255
#pragma unroll
    for (int ne = 0; ne < 16; ne++)
        step(ne, 15, ne <= 13, false, ne <= 13 ? 0 : (ne == 14 ? 2 : 3));

    // ---- bias: one MFMA k-step, operands loaded straight to registers ----
    {
        bf16x8 acw[4];
#pragma unroll
        for (int mt = 0; mt < 4; mt++) {
            bf16x8 v;
#pragma unroll
            for (int j = 0; j < 8; j++) v[j] = (bf16)0.f;
            if (lq < 2) {                  // k = lq*8+j in 0..15 real, else 0
                int row = m0 + wm * 64 + mt * 16 + lr;
                f32x4 a = *(const f32x4*)(cw + (size_t)row * NEXP + lq * 8);
                f32x4 b = *(const f32x4*)(cw + (size_t)row * NEXP + lq * 8 + 4);
#pragma unroll
                for (int j = 0; j < 4; j++) { v[j] = (bf16)a[j]; v[4 + j] = (bf16)b[j]; }
            }
            acw[mt] = v;
        }
        bf16x8 bb[2];
#pragma unroll
        for (int nt = 0; nt < 2; nt++) {
            bf16x8 v;
#pragma unroll
            for (int j = 0; j < 8; j++) v[j] = (bf16)0.f;
            if (lq < 2) {
                int col = n0 + wn * 32 + nt * 16 + lr;
#pragma unroll
                for (int j = 0; j < 8; j++)
                    v[j] = (bf16)bias[(size_t)(lq * 8 + j) * OUT_DIM + col];
            }
            bb[nt] = v;
        }
#pragma unroll
        for (int mt = 0; mt < 4; mt++)
#pragma unroll
            for (int nt = 0; nt < 2; nt++)
                acc[mt][nt] = __builtin_amdgcn_mfma_f32_16x16x32_bf16(
                    acw[mt], bb[nt], acc[mt][nt], 0, 0, 0);
    }

    // epilogue: relu + store (C/D: col = lane&15, row = quad*4 + reg)
#pragma unroll
    for (int mt = 0; mt < 4; mt++) {
        int row = m0 + wm * 64 + mt * 16 + lq * 4;
#pragma unroll
        for (int nt = 0; nt < 2; nt++) {
            int col = n0 + wn * 32 + nt * 16 + lr;
#pragma unroll
            for (int r2 = 0; r2 < 4; r2++) {
                float v = acc[mt][nt][r2];
                out[(size_t)(row + r2) * OUT_DIM + col] = v > 0.f ? v : 0.f;
            }
        }
    }
}

// ---------------------------------------------------------------------------
// Insurance fallback if ws_size is too small.
// ---------------------------------------------------------------------------
__global__ void fallback_kernel(const float* __restrict__ x, const float* __restrict__ cw,
                                const float* __restrict__ W, const float* __restrict__ bias,
                                float* __restrict__ out) {
    int o = blockIdx.x * 256 + threadIdx.x;
    int b = o >> 10, oc = o & 1023;
    const float* xr = x + (size_t)b * IN_DIM;
    float accv = 0.f;
    for (int n = 0; n < NEXP; n++) {
        const float* wr = W + (size_t)n * IN_DIM * OUT_DIM + oc;
        float z = 0.f;
        for (int i = 0; i < IN_DIM; i++) z += xr[i] * wr[(size_t)i * OUT_DIM];
        accv += cw[(size_t)b * NEXP + n] * (z + bias[n * OUT_DIM + oc]);
    }
    out[o] = accv > 0.f ? accv : 0.f;
}

extern "C" void kernel_launch(void* const* d_in, const int* in_sizes, int n_in,
                              void* d_out, int out_size, void* d_ws, size_t ws_size,
                              hipStream_t stream) {
    const float* x    = (const float*)d_in[0];
    const float* cw   = (const float*)d_in[1];
    const float* W    = (const float*)d_in[2];
    const float* bias = (const float*)d_in[3];
    float* out = (float*)d_out;

    const size_t wt_elems = (size_t)NEXP * IN_DIM * OUT_DIM;   // 32 MB bf16
    const size_t xt_elems = (size_t)BATCH * IN_DIM;            // 8 MB bf16
    if (ws_size < (wt_elems + xt_elems) * sizeof(bf16)) {
        fallback_kernel<<<(BATCH * OUT_DIM) / 256, 256, 0, stream>>>(x, cw, W, bias, out);
        return;
    }
    bf16* wt = (bf16*)d_ws;
    bf16* xt = wt + wt_elems;

    convert_all<<<4096 + 512, 256, 0, stream>>>(x, W, xt, wt);
    moe_gemm<<<dim3(16, 32), 256, 0, stream>>>(cw, bias, xt, wt, out);
}